// Round 9
// baseline (187.514 us; speedup 1.0000x reference)
//
#include <hip/hip_runtime.h>
#include <hip/hip_bf16.h>
#include <math.h>

#define D_DIM 2048
#define L_DIM 64
#define E_NUM 64
#define H_DIM 64

typedef float f32x4_t __attribute__((ext_vector_type(4)));
typedef __bf16 bf16x8_t __attribute__((ext_vector_type(8)));

// ---------------- workspace layout (bytes) ----------------
// WS_VPART: 256*64 f32 per-block gate partials   (64 KB)
// WS_META:  sel[2] (int) + g[2] (float)
// WS_WB:    tiled bf16 expert weights [32 kstep][128 row][64] (512 KB)
// WS_PART:  8*8192*128 f32 split-K GEMM partials (32 MB)
#define WS_VPART 0u
#define WS_META  (256u * 64u * 4u)
#define WS_WB    (WS_META + 64u)
#define WS_PART  (WS_WB + 128u * 2048u * 2u)

// wbt tiled layout (bf16 elem offsets), swizzle baked into storage:
//   chunk kc (16B) of row r within kstep tile lives at slot (kc ^ (r&7)):
//   wbt: kstep*8192 + row*64 + slot*8

// ---------------- kernel 1: fused u-partial + v-partial ----------------
// Block (bx, by): rows s0..s0+63, d-range [bx*1024, bx*1024+1024).
// acc[d] = sum_s x[s,d]*wout[s]  (in regs), then project onto Wg_in rows:
// vpart[by*2+bx][h] = sum_{d in range} Wg_in[h,d] * acc[d].
// Replaces the old k_upart + k_ufinish + k_v chain (2 fewer launches,
// no 1MB upart round-trip).
__global__ void k_upart(const float* __restrict__ x, const float* __restrict__ wout,
                        const float* __restrict__ wg_in, float* __restrict__ vpart) {
  __shared__ float sacc[1024];
  __shared__ float vred[64][4];
  const int t = threadIdx.x;            // 256 threads
  const int bx = blockIdx.x;            // 0..1 (d-half)
  const int d4 = (bx * 256 + t) * 4;
  const int s0 = blockIdx.y * 64;       // gridDim.y == 128
  const float* xp = x + (size_t)s0 * D_DIM + d4;
  float4 acc = make_float4(0.f, 0.f, 0.f, 0.f);
#pragma unroll 8
  for (int i = 0; i < 64; ++i) {
    const float w = wout[s0 + i];
    const float4 xv = *reinterpret_cast<const float4*>(xp + (size_t)i * D_DIM);
    acc.x += xv.x * w; acc.y += xv.y * w; acc.z += xv.z * w; acc.w += xv.w * w;
  }
  *reinterpret_cast<float4*>(&sacc[t * 4]) = acc;
  __syncthreads();
  // project: for each h, dot(Wg_in[h, d-range], sacc) via block-wide reduce
  const int wv = t >> 6, lane = t & 63;
  const float4* wg4 = reinterpret_cast<const float4*>(wg_in) + bx * 256;
  const float4* sa4 = reinterpret_cast<const float4*>(sacc);
  const float4 b = sa4[t];
#pragma unroll 4
  for (int h = 0; h < 64; ++h) {
    const float4 a = wg4[(size_t)h * 512 + t];
    float s = a.x * b.x + a.y * b.y + a.z * b.z + a.w * b.w;
#pragma unroll
    for (int off = 32; off; off >>= 1) s += __shfl_down(s, off, 64);
    if (lane == 0) vred[h][wv] = s;
  }
  __syncthreads();
  if (t < 64)
    vpart[((size_t)blockIdx.y * 2 + bx) * 64 + t] =
        vred[t][0] + vred[t][1] + vred[t][2] + vred[t][3];
}

// ---------------- kernel 2: reduce vpart -> scores, top-2, softmax ----------
__global__ void k_gate(const float* __restrict__ wg_lin, const float* __restrict__ vpart,
                       int* __restrict__ sel, float* __restrict__ g) {
  __shared__ float vq[4][H_DIM];
  __shared__ float vv[H_DIM];
  __shared__ float sc[E_NUM];
  const int t = threadIdx.x;  // 256 threads
  const int h = t & 63, q = t >> 6;
  {
    float s = 0.f;
#pragma unroll 8
    for (int c = q * 64; c < q * 64 + 64; ++c) s += vpart[(size_t)c * 64 + h];
    vq[q][h] = s;
  }
  __syncthreads();
  if (t < 64) vv[t] = vq[0][t] + vq[1][t] + vq[2][t] + vq[3][t];
  __syncthreads();
  if (t < 64) {
    float s = 0.f;
#pragma unroll 8
    for (int hh = 0; hh < H_DIM; ++hh) s += wg_lin[t * H_DIM + hh] * vv[hh];
    sc[t] = s;
  }
  __syncthreads();
  if (t == 0) {
    int b1 = 0; float m1 = sc[0];
    for (int e = 1; e < E_NUM; ++e) { if (sc[e] > m1) { m1 = sc[e]; b1 = e; } }
    int b2 = -1; float m2 = -3.4e38f;
    for (int e = 0; e < E_NUM; ++e) {
      if (e != b1 && sc[e] > m2) { m2 = sc[e]; b2 = e; }
    }
    const float e2 = expf(m2 - m1);
    const float g0 = 1.0f / (1.0f + e2);
    sel[0] = b1; sel[1] = b2;
    g[0] = g0; g[1] = 1.0f - g0;
  }
}

// ---------------- kernel 2c: tiled bf16 cast of selected experts ----------
__global__ void k_wb(const float* __restrict__ we, const int* __restrict__ sel,
                     __hip_bfloat16* __restrict__ wbt) {
  const int n = blockIdx.x;         // 128 rows = 2 experts x 64
  const int e = sel[n >> 6];
  const int l = n & 63;
  const float* src = we + ((size_t)e * L_DIM + l) * D_DIM;
  const int t = threadIdx.x;        // 256 threads, 8 elems each
  const int d8 = t * 8;
  const int kstep = d8 >> 6;
  const int kc = (d8 >> 3) & 7;
  const float4 a = reinterpret_cast<const float4*>(src)[2 * t];
  const float4 b = reinterpret_cast<const float4*>(src)[2 * t + 1];
  union { __hip_bfloat16 h[8]; uint4 u; } pk;
  pk.h[0] = __float2bfloat16(a.x); pk.h[1] = __float2bfloat16(a.y);
  pk.h[2] = __float2bfloat16(a.z); pk.h[3] = __float2bfloat16(a.w);
  pk.h[4] = __float2bfloat16(b.x); pk.h[5] = __float2bfloat16(b.y);
  pk.h[6] = __float2bfloat16(b.z); pk.h[7] = __float2bfloat16(b.w);
  const size_t off = (size_t)kstep * 8192 + n * 64 + ((kc ^ (n & 7)) * 8);
  *reinterpret_cast<uint4*>(wbt + off) = pk.u;
}

// ---------------- kernel 3: bf16 MFMA GEMM -> f32 partials ----------------
// (byte-identical to the R8-passing pipelined version)
__device__ __forceinline__ void async_ld16(const void* gp, void* lp) {
  __builtin_amdgcn_global_load_lds(
      (const __attribute__((address_space(1))) unsigned int*)gp,
      (__attribute__((address_space(3))) unsigned int*)lp, 16, 0, 0);
}

__device__ __forceinline__ float gelu_f(float v) {
  return 0.5f * v * (1.0f + erff(v * 0.70710678118654752440f));
}

__global__ __launch_bounds__(256, 4) void k_moe_gemm(
    const float* __restrict__ x, const __hip_bfloat16* __restrict__ wbt,
    float* __restrict__ part) {
  __shared__ __align__(16) unsigned char ldsA[8192];        // A 64x[8 slots x16B]
  __shared__ __align__(16) unsigned char ldsB[2][16384];    // B dbuf

  const int tid = threadIdx.x;
  const int w = tid >> 6, lane = tid & 63;
  const int wm = w >> 1, wn = w & 1;           // 2x2 wave grid, wave tile 32x64
  const int mb = blockIdx.x;                   // M-tile (64 rows)
  const int kg = blockIdx.y;                   // K-split 0..7 (256 K each)
  const int fr = lane & 15, fq = lane >> 4;
  const int m0 = mb * 64;

  const int c0 = tid, c1 = 256 + tid;
  const int r0_ = c0 >> 3, kc0 = c0 & 7, r1_ = c1 >> 3, kc1 = c1 & 7;
  unsigned char* aw0 = ldsA + r0_ * 128 + ((kc0 ^ (r0_ & 7)) << 4);
  unsigned char* aw1 = ldsA + r1_ * 128 + ((kc1 ^ (r1_ & 7)) << 4);
  const float* gA0 = x + (size_t)(m0 + r0_) * D_DIM + kc0 * 8;
  const float* gA1 = x + (size_t)(m0 + r1_) * D_DIM + kc1 * 8;

  f32x4_t acc[2][4];
#pragma unroll
  for (int mf = 0; mf < 2; ++mf)
#pragma unroll
    for (int nf = 0; nf < 4; ++nf) acc[mf][nf] = (f32x4_t){0.f, 0.f, 0.f, 0.f};

  union { __hip_bfloat16 h[8]; uint4 u; } pk;
  float4 ar[4];

  auto cvt_write = [&]() {
    pk.h[0] = __float2bfloat16(ar[0].x); pk.h[1] = __float2bfloat16(ar[0].y);
    pk.h[2] = __float2bfloat16(ar[0].z); pk.h[3] = __float2bfloat16(ar[0].w);
    pk.h[4] = __float2bfloat16(ar[1].x); pk.h[5] = __float2bfloat16(ar[1].y);
    pk.h[6] = __float2bfloat16(ar[1].z); pk.h[7] = __float2bfloat16(ar[1].w);
    *reinterpret_cast<uint4*>(aw0) = pk.u;
    pk.h[0] = __float2bfloat16(ar[2].x); pk.h[1] = __float2bfloat16(ar[2].y);
    pk.h[2] = __float2bfloat16(ar[2].z); pk.h[3] = __float2bfloat16(ar[2].w);
    pk.h[4] = __float2bfloat16(ar[3].x); pk.h[5] = __float2bfloat16(ar[3].y);
    pk.h[6] = __float2bfloat16(ar[3].z); pk.h[7] = __float2bfloat16(ar[3].w);
    *reinterpret_cast<uint4*>(aw1) = pk.u;
  };

  {
    const int k0 = (kg * 4) * 64;
    ar[0] = *reinterpret_cast<const float4*>(gA0 + k0);
    ar[1] = *reinterpret_cast<const float4*>(gA0 + k0 + 4);
    ar[2] = *reinterpret_cast<const float4*>(gA1 + k0);
    ar[3] = *reinterpret_cast<const float4*>(gA1 + k0 + 4);
#pragma unroll
    for (int ph = 0; ph < 4; ++ph) {
      const int c = ph * 256 + tid;
      async_ld16(wbt + (size_t)(kg * 4) * 8192 + c * 8, &ldsB[0][c * 16]);
    }
    cvt_write();
    __syncthreads();
  }

  for (int kk = 0; kk < 4; ++kk) {
    const int cur = kk & 1;
    union fragu { uint4 u; bf16x8_t v; };
    fragu af[2][2], bf_[4][2];
#pragma unroll
    for (int mf = 0; mf < 2; ++mf)
#pragma unroll
      for (int ks = 0; ks < 2; ++ks) {
        const int arr = wm * 32 + mf * 16 + fr;
        const int kq = ks * 4 + fq;
        af[mf][ks].u = *reinterpret_cast<const uint4*>(
            ldsA + arr * 128 + ((kq ^ (arr & 7)) * 16));
      }
#pragma unroll
    for (int nf = 0; nf < 4; ++nf)
#pragma unroll
      for (int ks = 0; ks < 2; ++ks) {
        const int br = wn * 64 + nf * 16 + fr;
        const int kq = ks * 4 + fq;
        bf_[nf][ks].u = *reinterpret_cast<const uint4*>(
            ldsB[cur] + br * 128 + ((kq ^ (br & 7)) * 16));
      }
    if (kk < 3) {
      const int k0n = (kg * 4 + kk + 1) * 64;
      ar[0] = *reinterpret_cast<const float4*>(gA0 + k0n);
      ar[1] = *reinterpret_cast<const float4*>(gA0 + k0n + 4);
      ar[2] = *reinterpret_cast<const float4*>(gA1 + k0n);
      ar[3] = *reinterpret_cast<const float4*>(gA1 + k0n + 4);
      __builtin_amdgcn_sched_barrier(0);
#pragma unroll
      for (int ph = 0; ph < 4; ++ph) {
        const int c = ph * 256 + tid;
        async_ld16(wbt + (size_t)(kg * 4 + kk + 1) * 8192 + c * 8,
                   &ldsB[cur ^ 1][c * 16]);
      }
      __builtin_amdgcn_sched_barrier(0);
    }
#pragma unroll
    for (int mf = 0; mf < 2; ++mf)
#pragma unroll
      for (int nf = 0; nf < 4; ++nf) {
        acc[mf][nf] = __builtin_amdgcn_mfma_f32_16x16x32_bf16(
            af[mf][0].v, bf_[nf][0].v, acc[mf][nf], 0, 0, 0);
        acc[mf][nf] = __builtin_amdgcn_mfma_f32_16x16x32_bf16(
            af[mf][1].v, bf_[nf][1].v, acc[mf][nf], 0, 0, 0);
      }
    asm volatile("s_waitcnt lgkmcnt(0)" ::: "memory");
    __builtin_amdgcn_s_barrier();
    __builtin_amdgcn_sched_barrier(0);
    if (kk < 3) {
      cvt_write();
    }
    asm volatile("s_waitcnt vmcnt(0) lgkmcnt(0)" ::: "memory");
    __builtin_amdgcn_s_barrier();
    __builtin_amdgcn_sched_barrier(0);
  }

#pragma unroll
  for (int mf = 0; mf < 2; ++mf)
#pragma unroll
    for (int nf = 0; nf < 4; ++nf)
#pragma unroll
      for (int reg = 0; reg < 4; ++reg) {
        const int r = m0 + wm * 32 + mf * 16 + fq * 4 + reg;
        const int c = wn * 64 + nf * 16 + fr;
        part[((size_t)kg * 8192 + r) * 128 + c] = acc[mf][nf][reg];
      }
}

// ---------------- kernel 4: reduce partials + normalize + gelu + combine ----
__global__ __launch_bounds__(256) void k_finish(const float* __restrict__ part,
                                                const float* __restrict__ gw,
                                                float* __restrict__ out) {
  __shared__ float z[32 * 132];
  __shared__ float ps[32 * 8];
  const int tid = threadIdx.x;
  const int m0 = blockIdx.x * 32;   // 256 blocks
  const float g0 = gw[0], g1 = gw[1];
  const size_t KSTRIDE = (size_t)8192 * 128;
#pragma unroll
  for (int p = 0; p < 4; ++p) {
    const int idx = p * 256 + tid;
    const int r = idx >> 5, c4 = (idx & 31) * 4;
    const float* pp = part + ((size_t)(m0 + r)) * 128 + c4;
    f32x4_t s = (f32x4_t){0.f, 0.f, 0.f, 0.f};
#pragma unroll
    for (int kgi = 0; kgi < 8; ++kgi)
      s = s + *reinterpret_cast<const f32x4_t*>(pp + kgi * KSTRIDE);
    z[r * 132 + c4 + 0] = s[0];
    z[r * 132 + c4 + 1] = s[1];
    z[r * 132 + c4 + 2] = s[2];
    z[r * 132 + c4 + 3] = s[3];
  }
  __syncthreads();
  {
    const int r = tid >> 3, seg = tid & 7;
    float s = 0.f;
#pragma unroll
    for (int i2 = 0; i2 < 16; ++i2) {
      const float t2 = z[r * 132 + seg * 16 + i2];
      s += t2 * t2;
    }
    ps[r * 8 + seg] = s;
  }
  __syncthreads();
  {
    const int r = tid >> 3, j = tid & 7;
    const float s0 = ps[r * 8 + 0] + ps[r * 8 + 1] + ps[r * 8 + 2] + ps[r * 8 + 3];
    const float s1 = ps[r * 8 + 4] + ps[r * 8 + 5] + ps[r * 8 + 6] + ps[r * 8 + 7];
    const float i0 = 1.0f / fmaxf(sqrtf(s0), 1e-12f);
    const float i1 = 1.0f / fmaxf(sqrtf(s1), 1e-12f);
    float o[8];
#pragma unroll
    for (int i2 = 0; i2 < 8; ++i2) {
      const int c = j * 8 + i2;
      const float za = z[r * 132 + c] * i0;
      const float zb2 = z[r * 132 + 64 + c] * i1;
      o[i2] = g0 * gelu_f(za) + g1 * gelu_f(zb2);
    }
    float4* op = reinterpret_cast<float4*>(out + (size_t)(m0 + r) * 64 + j * 8);
    op[0] = make_float4(o[0], o[1], o[2], o[3]);
    op[1] = make_float4(o[4], o[5], o[6], o[7]);
  }
}

// ---------------- launch ----------------
extern "C" void kernel_launch(void* const* d_in, const int* in_sizes, int n_in,
                              void* d_out, int out_size, void* d_ws, size_t ws_size,
                              hipStream_t stream) {
  (void)in_sizes; (void)n_in; (void)out_size; (void)ws_size;
  const float* x      = (const float*)d_in[0];
  const float* wg_in  = (const float*)d_in[1];
  const float* wg_lin = (const float*)d_in[2];
  const float* wg_out = (const float*)d_in[3];
  const float* we     = (const float*)d_in[4];
  float* out = (float*)d_out;
  char* ws = (char*)d_ws;

  float* vpart = (float*)(ws + WS_VPART);
  int*   sel   = (int*)(ws + WS_META);
  float* g     = (float*)(ws + WS_META + 8);
  __hip_bfloat16* wbt = (__hip_bfloat16*)(ws + WS_WB);
  float* part = (float*)(ws + WS_PART);

  k_upart  <<<dim3(2, 128), 256, 0, stream>>>(x, wg_out, wg_in, vpart);
  k_gate   <<<1, 256, 0, stream>>>(wg_lin, vpart, sel, g);
  k_wb     <<<128, 256, 0, stream>>>(we, sel, wbt);
  k_moe_gemm<<<dim3(128, 8), 256, 0, stream>>>(x, wbt, part);
  k_finish <<<256, 256, 0, stream>>>(part, g, out);
}